// Round 4
// baseline (59.016 us; speedup 1.0000x reference)
//
#include <hip/hip_runtime.h>

#define HGT 128
#define WID 128
#define HW  (HGT * WID)          // 16384
#define CCH 64
#define NHEADS 4
#define NA 36                    // HEADS * KK
#define NB 4

// workspace layout (floats)
#define WR_FG_OFF 0              // 64*36
#define WR_BG_OFF 2304           // 64*36
#define BIAS_OFF  4608           // 36
#define V_OFF     4672           // B*64*HW = 4194304
#define ATTN_OFF  (4672 + 4194304)  // B*36*HW = 2359296

// ---------------------------------------------------------------------------
// Kernel 0: reduce attention weights over the summed i-axis.
// Wr[c][h*9+j] = sum_i W[c][h*81 + i*9 + j];  bias_attn[hj] = sum_i (bfg+bbg)
// ---------------------------------------------------------------------------
__global__ void reduce_weights_kernel(const float* __restrict__ Wfg,
                                      const float* __restrict__ bfg,
                                      const float* __restrict__ Wbg,
                                      const float* __restrict__ bbg,
                                      float* __restrict__ ws) {
    int idx = blockIdx.x * 256 + threadIdx.x;
    if (idx < 2 * 2304) {
        int which = idx / 2304;
        int r = idx % 2304;
        int c = r / 36, hj = r % 36;
        int h = hj / 9, j = hj % 9;
        const float* W = which ? Wbg : Wfg;
        float s = 0.f;
        #pragma unroll
        for (int i = 0; i < 9; i++) s += W[c * 324 + h * 81 + i * 9 + j];
        ws[(which ? WR_BG_OFF : WR_FG_OFF) + r] = s;
    } else if (idx < 2 * 2304 + 36) {
        int hj = idx - 4608;
        int h = hj / 9, j = hj % 9;
        float s = 0.f;
        #pragma unroll
        for (int i = 0; i < 9; i++)
            s += bfg[h * 81 + i * 9 + j] + bbg[h * 81 + i * 9 + j];
        ws[BIAS_OFF + hj] = s;
    }
}

// ---------------------------------------------------------------------------
// Kernel 1: per-pixel projections — scalar-pipe weights, K$-friendly.
// g = blockIdx & 3 selects the output group for the WHOLE block (all 4 waves)
// so each CU's resident blocks share one 8.7 KB weight slice (fits K$).
// Thread = 1 pixel; block = 256 pixels; 1024 blocks = 4 blocks/CU.
// Wave computes v-outputs [g*16,g*16+16) and attn-outputs [g*9,g*9+9).
// ---------------------------------------------------------------------------
__global__ __launch_bounds__(256, 4) void proj_kernel(
        const float* __restrict__ x, const float* __restrict__ fg,
        const float* __restrict__ bg, const float* __restrict__ Wv,
        const float* __restrict__ bv, const float* __restrict__ ws,
        float* __restrict__ v_out, float* __restrict__ attn_out) {
    int tid = threadIdx.x;
    int g = __builtin_amdgcn_readfirstlane(blockIdx.x & 3);
    int chunk = blockIdx.x >> 2;                  // 0..255
    int p = chunk * 256 + tid;                    // global pixel
    int b = __builtin_amdgcn_readfirstlane(p >> 14);
    int l = p & (HW - 1);
    const size_t binoff = (size_t)b * CCH * HW;

    // ---------------- v part: outputs [g*16, g*16+16) ----------------
    int o0 = g * 16;
    const float* xb = x + binoff + l;
    float accv[16];
    #pragma unroll
    for (int o = 0; o < 16; o++) accv[o] = bv[o0 + o];

    #pragma unroll 2
    for (int c0 = 0; c0 < 64; c0 += 8) {
        float xr[8];
        #pragma unroll
        for (int cc = 0; cc < 8; cc++) xr[cc] = xb[(size_t)(c0 + cc) * HW];
        #pragma unroll
        for (int cc = 0; cc < 8; cc++) {
            #pragma unroll
            for (int o = 0; o < 16; o++)
                accv[o] += xr[cc] * Wv[(c0 + cc) * 64 + o0 + o];  // s_load, K$-hot
        }
    }
    float* vo = v_out + binoff + (size_t)o0 * HW + l;
    #pragma unroll
    for (int o = 0; o < 16; o++) vo[(size_t)o * HW] = accv[o];

    // -------------- attn part: outputs [g*9, g*9+9) ------------------
    int a0 = g * 9;
    const float* fb = fg + binoff + l;
    const float* gb = bg + binoff + l;
    const float* Wf = ws + WR_FG_OFF;
    const float* Wg = ws + WR_BG_OFF;

    float acca[9];
    #pragma unroll
    for (int o = 0; o < 9; o++) acca[o] = ws[BIAS_OFF + a0 + o];

    #pragma unroll 2
    for (int c0 = 0; c0 < 64; c0 += 8) {
        float fr[8], gr[8];
        #pragma unroll
        for (int cc = 0; cc < 8; cc++) {
            fr[cc] = fb[(size_t)(c0 + cc) * HW];
            gr[cc] = gb[(size_t)(c0 + cc) * HW];
        }
        #pragma unroll
        for (int cc = 0; cc < 8; cc++) {
            #pragma unroll
            for (int o = 0; o < 9; o++) {
                acca[o] += fr[cc] * Wf[(c0 + cc) * 36 + a0 + o];  // s_load, K$-hot
                acca[o] += gr[cc] * Wg[(c0 + cc) * 36 + a0 + o];  // s_load, K$-hot
            }
        }
    }
    float* ao = attn_out + (size_t)b * NA * HW + (size_t)a0 * HW + l;
    #pragma unroll
    for (int o = 0; o < 9; o++) ao[(size_t)o * HW] = acca[o];
}

// ---------------------------------------------------------------------------
// Kernel 2: aggregation.
//   out[b][c][l] = sum_j attn[b][h(c)*9+j][l] * v[b][c][nbr_j(l)]
// One thread per (pixel, head); 16 channels per thread.
// ---------------------------------------------------------------------------
__global__ __launch_bounds__(256) void agg_kernel(
        const float* __restrict__ v, const float* __restrict__ attn,
        float* __restrict__ out) {
    int idx = blockIdx.x * 256 + threadIdx.x;     // B*4*HW threads
    int l = idx & (HW - 1);
    int rest = idx >> 14;
    int b = rest >> 2;
    int h = rest & 3;
    int y = l >> 7, xx = l & 127;

    const float* ab = attn + ((size_t)b * 36 + h * 9) * HW + l;
    float w[9];
    int off[9];
    #pragma unroll
    for (int j = 0; j < 9; j++) {
        w[j] = ab[(size_t)j * HW];
        int dy = j / 3 - 1, dx = j % 3 - 1;
        int yy = y + dy, xc = xx + dx;
        bool valid = (yy >= 0) && (yy < HGT) && (xc >= 0) && (xc < WID);
        off[j] = valid ? (yy * WID + xc) : l;
        if (!valid) w[j] = 0.f;
    }

    const float* vb = v + ((size_t)b * 64 + h * 16) * HW;
    float* ob = out + ((size_t)b * 64 + h * 16) * HW + l;
    #pragma unroll 4
    for (int c2 = 0; c2 < 16; c2++) {
        const float* vc = vb + (size_t)c2 * HW;
        float acc = 0.f;
        #pragma unroll
        for (int j = 0; j < 9; j++) acc += w[j] * vc[off[j]];
        ob[(size_t)c2 * HW] = acc;
    }
}

extern "C" void kernel_launch(void* const* d_in, const int* in_sizes, int n_in,
                              void* d_out, int out_size, void* d_ws, size_t ws_size,
                              hipStream_t stream) {
    const float* x   = (const float*)d_in[0];
    const float* fg  = (const float*)d_in[1];
    const float* bg  = (const float*)d_in[2];
    const float* Wv  = (const float*)d_in[3];
    const float* bv  = (const float*)d_in[4];
    const float* Wfg = (const float*)d_in[5];
    const float* bfg = (const float*)d_in[6];
    const float* Wbg = (const float*)d_in[7];
    const float* bbg = (const float*)d_in[8];

    float* ws  = (float*)d_ws;
    float* out = (float*)d_out;

    float* v_ws    = ws + V_OFF;
    float* attn_ws = ws + ATTN_OFF;

    // 0) reduce attention weights (4644 work items)
    reduce_weights_kernel<<<19, 256, 0, stream>>>(Wfg, bfg, Wbg, bbg, ws);

    // 1) projections: group-per-block, 256 pixels per block -> 1024 blocks
    proj_kernel<<<1024, 256, 0, stream>>>(x, fg, bg, Wv, bv, ws, v_ws, attn_ws);

    // 2) aggregation: one thread per (pixel, head)
    int np = NB * HW;                      // 65536
    agg_kernel<<<np * 4 / 256, 256, 0, stream>>>(v_ws, attn_ws, out);
}

// Round 5
// 33.545 us; speedup vs baseline: 1.7593x; 1.7593x over previous
//
#include <hip/hip_runtime.h>
#include <hip/hip_bf16.h>

#define HGT 128
#define WID 128
#define HW  (HGT * WID)          // 16384
#define CCH 64
#define NHEADS 4
#define NA 36                    // HEADS * KK
#define NB 4

typedef __attribute__((ext_vector_type(8))) short bf16x8;
typedef __attribute__((ext_vector_type(4))) float f32x4;

// workspace layout (float offsets)
// WF: 20 weight-frag tiles (8 for v-GEMM, 12 for attn-GEMM), each 64 lanes x 8 bf16
#define WF_OFF   0               // 20*64*8 ushort = 10240 ushort = 5120 floats
#define BA_OFF   5120            // 48 floats (reduced attn bias, padded)
#define V_OFF    5184            // B*64*HW floats
#define ATTN_OFF (5184 + 4194304)// B*36*HW floats

__device__ inline short f2bf(float f) {
    // round-to-nearest-even bf16 truncation
    unsigned u = __float_as_uint(f);
    unsigned r = (u + 0x7fffu + ((u >> 16) & 1u)) >> 16;
    return (short)r;
}

// ---------------------------------------------------------------------------
// Prep kernel: build MFMA A-operand fragments (transposed weights) in the
// exact per-lane layout, bf16, plus the i-reduced attn bias.
//   GEMM1 (v):    A1[t = nt*2+kf]: elem(lane,j) = Wv[k][n],  k=kf*32+(lane>>4)*8+j, n=nt*16+(lane&15)
//   GEMM2 (attn): A2[t = nt*4+kf]: elem = Wr[k][n]; rows 0-63 from Wfg (i-reduced),
//                 rows 64-127 from Wbg; cols>=36 zero-padded.
// ---------------------------------------------------------------------------
__global__ void prep_kernel(const float* __restrict__ Wv,
                            const float* __restrict__ Wfg,
                            const float* __restrict__ bfg,
                            const float* __restrict__ Wbg,
                            const float* __restrict__ bbg,
                            float* __restrict__ ws) {
    int idx = blockIdx.x * 256 + threadIdx.x;
    unsigned short* wf = (unsigned short*)ws;
    if (idx < 20 * 64 * 8) {
        int j    = idx & 7;
        int lane = (idx >> 3) & 63;
        int t    = idx >> 9;
        int lo = lane & 15, hi = lane >> 4;
        float val;
        if (t < 8) {
            int nt = t >> 1, kf = t & 1;
            int k = kf * 32 + hi * 8 + j;
            int n = nt * 16 + lo;
            val = Wv[k * 64 + n];
        } else {
            int t2 = t - 8;
            int nt = t2 >> 2, kf = t2 & 3;
            int k = kf * 32 + hi * 8 + j;      // 0..127
            int n = nt * 16 + lo;              // 0..47
            if (n >= 36) {
                val = 0.f;
            } else {
                int h = n / 9, jj = n % 9;
                const float* W = (k < 64) ? Wfg : Wbg;
                int c = (k < 64) ? k : k - 64;
                float s = 0.f;
                #pragma unroll
                for (int i = 0; i < 9; i++) s += W[c * 324 + h * 81 + i * 9 + jj];
                val = s;
            }
        }
        wf[idx] = (unsigned short)f2bf(val);
    } else if (idx < 20 * 64 * 8 + 48) {
        int n = idx - 20 * 64 * 8;
        float s = 0.f;
        if (n < 36) {
            int h = n / 9, jj = n % 9;
            #pragma unroll
            for (int i = 0; i < 9; i++)
                s += bfg[h * 81 + i * 9 + jj] + bbg[h * 81 + i * 9 + jj];
        }
        ws[BA_OFF + n] = s;
    }
}

// ---------------------------------------------------------------------------
// Main projection kernel via bf16 MFMA (computes C^T so stores coalesce).
// Block = 4 waves; each wave owns one 16-pixel M-tile.
//   v[b][o][p]    : D = A1(WvT) x B(x),        o-tiles 0..3,  K=64  (2 frags)
//   attn[b][hj][p]: D = A2(WrT) x B(fg|bg),    hj-tiles 0..2, K=128 (4 frags)
// D layout: col = lane&15 = pixel, row = (lane>>4)*4 + r = output channel.
// ---------------------------------------------------------------------------
__global__ __launch_bounds__(256) void proj_mfma(
        const float* __restrict__ x, const float* __restrict__ fg,
        const float* __restrict__ bg, const float* __restrict__ bv,
        const float* __restrict__ ws,
        float* __restrict__ v_out, float* __restrict__ attn_out) {
    int tid  = threadIdx.x;
    int wave = tid >> 6, lane = tid & 63;
    int lo = lane & 15, hi = lane >> 4;

    int p0 = blockIdx.x * 64 + wave * 16;     // 16-pixel tile
    int b  = p0 >> 14;                        // uniform per block (64 | 16384)
    int l0 = p0 & (HW - 1);
    const size_t bin = (size_t)b * CCH * HW;

    // ---- weight A-frags: coalesced 16B loads, held in VGPRs ----
    const unsigned short* wf = (const unsigned short*)ws;
    bf16x8 a1[8];
    #pragma unroll
    for (int t = 0; t < 8; t++)
        a1[t] = *(const bf16x8*)(wf + ((size_t)t * 64 + lane) * 8);
    bf16x8 a2[12];
    #pragma unroll
    for (int t = 0; t < 12; t++)
        a2[t] = *(const bf16x8*)(wf + ((size_t)(8 + t) * 64 + lane) * 8);

    int pix = l0 + lo;

    // ---- v GEMM ----
    const float* xp = x + bin + pix;
    bf16x8 bx[2];
    #pragma unroll
    for (int kf = 0; kf < 2; kf++)
        #pragma unroll
        for (int j = 0; j < 8; j++)
            bx[kf][j] = f2bf(xp[(size_t)(kf * 32 + hi * 8 + j) * HW]);

    f32x4 av[4];
    #pragma unroll
    for (int nt = 0; nt < 4; nt++)
        #pragma unroll
        for (int r = 0; r < 4; r++)
            av[nt][r] = bv[nt * 16 + hi * 4 + r];

    #pragma unroll
    for (int nt = 0; nt < 4; nt++) {
        av[nt] = __builtin_amdgcn_mfma_f32_16x16x32_bf16(a1[nt * 2 + 0], bx[0], av[nt], 0, 0, 0);
        av[nt] = __builtin_amdgcn_mfma_f32_16x16x32_bf16(a1[nt * 2 + 1], bx[1], av[nt], 0, 0, 0);
    }

    float* vo = v_out + bin + pix;
    #pragma unroll
    for (int nt = 0; nt < 4; nt++)
        #pragma unroll
        for (int r = 0; r < 4; r++)
            vo[(size_t)(nt * 16 + hi * 4 + r) * HW] = av[nt][r];

    // ---- attn GEMM (K = 128: fg channels then bg channels) ----
    const float* fp = fg + bin + pix;
    const float* gp = bg + bin + pix;
    bf16x8 b2[4];
    #pragma unroll
    for (int kf = 0; kf < 2; kf++)
        #pragma unroll
        for (int j = 0; j < 8; j++)
            b2[kf][j] = f2bf(fp[(size_t)(kf * 32 + hi * 8 + j) * HW]);
    #pragma unroll
    for (int kf = 0; kf < 2; kf++)
        #pragma unroll
        for (int j = 0; j < 8; j++)
            b2[2 + kf][j] = f2bf(gp[(size_t)(kf * 32 + hi * 8 + j) * HW]);

    f32x4 aa[3];
    #pragma unroll
    for (int nt = 0; nt < 3; nt++)
        #pragma unroll
        for (int r = 0; r < 4; r++)
            aa[nt][r] = ws[BA_OFF + nt * 16 + hi * 4 + r];

    #pragma unroll
    for (int nt = 0; nt < 3; nt++)
        #pragma unroll
        for (int kf = 0; kf < 4; kf++)
            aa[nt] = __builtin_amdgcn_mfma_f32_16x16x32_bf16(a2[nt * 4 + kf], b2[kf], aa[nt], 0, 0, 0);

    float* ao = attn_out + (size_t)b * NA * HW + pix;
    #pragma unroll
    for (int nt = 0; nt < 3; nt++)
        #pragma unroll
        for (int r = 0; r < 4; r++) {
            int n = nt * 16 + hi * 4 + r;
            if (n < 36) ao[(size_t)n * HW] = aa[nt][r];
        }
}

// ---------------------------------------------------------------------------
// Aggregation: out[b][c][l] = sum_j attn[b][h(c)*9+j][l] * v[b][c][nbr_j(l)]
// ---------------------------------------------------------------------------
__global__ __launch_bounds__(256) void agg_kernel(
        const float* __restrict__ v, const float* __restrict__ attn,
        float* __restrict__ out) {
    int idx = blockIdx.x * 256 + threadIdx.x;     // B*4*HW threads
    int l = idx & (HW - 1);
    int rest = idx >> 14;
    int b = rest >> 2;
    int h = rest & 3;
    int y = l >> 7, xx = l & 127;

    const float* ab = attn + ((size_t)b * 36 + h * 9) * HW + l;
    float w[9];
    int off[9];
    #pragma unroll
    for (int j = 0; j < 9; j++) {
        w[j] = ab[(size_t)j * HW];
        int dy = j / 3 - 1, dx = j % 3 - 1;
        int yy = y + dy, xc = xx + dx;
        bool valid = (yy >= 0) && (yy < HGT) && (xc >= 0) && (xc < WID);
        off[j] = valid ? (yy * WID + xc) : l;
        if (!valid) w[j] = 0.f;
    }

    const float* vb = v + ((size_t)b * 64 + h * 16) * HW;
    float* ob = out + ((size_t)b * 64 + h * 16) * HW + l;
    #pragma unroll 4
    for (int c2 = 0; c2 < 16; c2++) {
        const float* vc = vb + (size_t)c2 * HW;
        float acc = 0.f;
        #pragma unroll
        for (int j = 0; j < 9; j++) acc += w[j] * vc[off[j]];
        ob[(size_t)c2 * HW] = acc;
    }
}

extern "C" void kernel_launch(void* const* d_in, const int* in_sizes, int n_in,
                              void* d_out, int out_size, void* d_ws, size_t ws_size,
                              hipStream_t stream) {
    const float* x   = (const float*)d_in[0];
    const float* fg  = (const float*)d_in[1];
    const float* bg  = (const float*)d_in[2];
    const float* Wv  = (const float*)d_in[3];
    const float* bv  = (const float*)d_in[4];
    const float* Wfg = (const float*)d_in[5];
    const float* bfg = (const float*)d_in[6];
    const float* Wbg = (const float*)d_in[7];
    const float* bbg = (const float*)d_in[8];

    float* ws  = (float*)d_ws;
    float* out = (float*)d_out;

    float* v_ws    = ws + V_OFF;
    float* attn_ws = ws + ATTN_OFF;

    // 0) pack weight fragments + reduced bias (10288 work items)
    prep_kernel<<<41, 256, 0, stream>>>(Wv, Wfg, bfg, Wbg, bbg, ws);

    // 1) MFMA projections: 64 pixels per block -> 1024 blocks
    proj_mfma<<<1024, 256, 0, stream>>>(x, fg, bg, bv, ws, v_ws, attn_ws);

    // 2) aggregation: one thread per (pixel, head)
    int np = NB * HW;                      // 65536
    agg_kernel<<<np * 4 / 256, 256, 0, stream>>>(v_ws, attn_ws, out);
}